// Round 6
// baseline (343.668 us; speedup 1.0000x reference)
//
#include <hip/hip_runtime.h>
#include <hip/hip_bf16.h>
#include <cstdint>
#include <cstddef>

typedef unsigned short u16;
typedef __attribute__((ext_vector_type(8))) __bf16 bf16x8;
typedef __attribute__((ext_vector_type(4))) float floatx4;

#define B_    2
#define S_    2048
#define HID_  2048
#define NH_   16
#define NKV_  4
#define HD_   128
#define QKVN_ 3072   // NH*HD + 2*NKV*HD

__device__ __forceinline__ float bf2f(u16 u) {
  union { unsigned int i; float f; } v; v.i = ((unsigned int)u) << 16; return v.f;
}
__device__ __forceinline__ u16 f2bf(float f) {
  union { float f; unsigned int i; } v; v.f = f;
  unsigned int u = v.i;
  return (u16)((u + 0x7fffu + ((u >> 16) & 1u)) >> 16);  // RNE
}

// async global->LDS, 16B per lane; lane i lands at (wave-uniform base) + i*16.
#define GLOAD_LDS16(gp, lp)                                                  \
  __builtin_amdgcn_global_load_lds(                                          \
      (__attribute__((address_space(1))) void*)(gp),                         \
      (__attribute__((address_space(3))) void*)(lp), 16, 0, 0)

// ---------------------------------------------------------------------------
// f32 -> bf16 (RNE), 8 elements/thread, 16B stores. n % 2048 == 0.
// ---------------------------------------------------------------------------
__global__ __launch_bounds__(256)
void cast_f32_bf16(const float* __restrict__ in, u16* __restrict__ out, int n)
{
  const int i = (blockIdx.x * 256 + threadIdx.x) * 8;
  if (i >= n) return;
  const float4 a = *(const float4*)(in + i);
  const float4 b = *(const float4*)(in + i + 4);
  union { u16 h[8]; uint4 v; } o;
  o.h[0] = f2bf(a.x); o.h[1] = f2bf(a.y); o.h[2] = f2bf(a.z); o.h[3] = f2bf(a.w);
  o.h[4] = f2bf(b.x); o.h[5] = f2bf(b.y); o.h[6] = f2bf(b.z); o.h[7] = f2bf(b.w);
  *(uint4*)(out + i) = o.v;
}

// ---------------------------------------------------------------------------
// 256x256 8-PHASE GEMM (T2+T3+T4+T5): C[M,N] = A[M,K] @ W[N,K]^T, bf16 in,
// fp32 accum. 512 threads = 8 waves (2M x 4N), 128x64 out/wave, BK=64,
// 2 K-tiles per iteration, 8 phases/iter. LDS 128 KB:
//   lA: [2 buf][2 half(128 rows)][128*64]   lB: same for W rows.
// Swizzle: LDS k-chunk slot s holds global chunk s^(row&7) (pre-swizzled
// global source; ds_read applies same XOR — both-sides involution, rule #21).
// Staging ledger (per phase, steady state; lead >= 3 phases, every overwrite
// >= 1 barrier after its last reader's lgkm drain):
//   ph0: A0(t+1)  ph1: A1(t+1)  ph2: B0(t+2)  ph3: B1(t+2)
//   ph4: A0(t+2)  ph5: A1(t+2)  ph6: B0(t+3)  ph7: B1(t+3)
// vmcnt(4) at ph3 & ph7 ONLY (12 outstanding -> certify oldest 8 = the A+B
// pairs read next phase; youngest B pair stays in flight across barriers).
// Last iteration: skip dead stages, vmcnt(0). NT (=K/64) must be even.
// ---------------------------------------------------------------------------
#define STG_A(T, h)                                                          \
  { _Pragma("unroll") for (int p = 0; p < 2; ++p) {                          \
      const int L = p * 512 + tid; const int row = L >> 3, c = L & 7;        \
      GLOAD_LDS16(A + (size_t)(m0 + (h) * 128 + row) * lda + (T) * 64        \
                    + ((c ^ (row & 7)) * 8),                                 \
                  lA + ((T) & 1) * 16384 + (h) * 8192 + L * 8); } }
#define STG_B(T, h)                                                          \
  { _Pragma("unroll") for (int p = 0; p < 2; ++p) {                          \
      const int L = p * 512 + tid; const int row = L >> 3, c = L & 7;        \
      GLOAD_LDS16(W + (size_t)(n0 + (h) * 128 + row) * K + (T) * 64          \
                    + ((c ^ (row & 7)) * 8),                                 \
                  lB + ((T) & 1) * 16384 + (h) * 8192 + L * 8); } }
// frag reads (rows: A = wr*128+mf*16+l15, B = wc*64+nf*16+l15; &7 == l15&7)
#define RD_A(mf, kc, buf) (*(const bf16x8*)(lA + (buf) * 16384 + wr * 8192   \
    + ((mf) * 16 + l15) * 64 + (((kc) * 4 + quad) ^ (l15 & 7)) * 8))
#define RD_B(nf, kc, buf) (*(const bf16x8*)(lB + (buf) * 16384               \
    + (wc >> 1) * 8192 + ((wc & 1) * 64 + (nf) * 16 + l15) * 64              \
    + (((kc) * 4 + quad) ^ (l15 & 7)) * 8))
#define RDS_A03(buf) { _Pragma("unroll") for (int ii = 0; ii < 4; ++ii) {    \
    aR[ii][0] = RD_A(ii, 0, buf); aR[ii][1] = RD_A(ii, 1, buf); } }
#define RDS_A47(buf) { _Pragma("unroll") for (int ii = 0; ii < 4; ++ii) {    \
    aR[ii][0] = RD_A(ii + 4, 0, buf); aR[ii][1] = RD_A(ii + 4, 1, buf); } }
#define RDS_B01(buf) { bR[0][0] = RD_B(0, 0, buf); bR[0][1] = RD_B(0, 1, buf); \
    bR[1][0] = RD_B(1, 0, buf); bR[1][1] = RD_B(1, 1, buf); }
#define RDS_B23(buf) { bR[2][0] = RD_B(2, 0, buf); bR[2][1] = RD_B(2, 1, buf); \
    bR[3][0] = RD_B(3, 0, buf); bR[3][1] = RD_B(3, 1, buf); }
#define MFMAQ(iB, jB)                                                        \
  { _Pragma("unroll") for (int ii = 0; ii < 4; ++ii)                         \
    _Pragma("unroll") for (int jj = 0; jj < 2; ++jj)                         \
    _Pragma("unroll") for (int kc = 0; kc < 2; ++kc)                         \
      acc[(iB) + ii][(jB) + jj] = __builtin_amdgcn_mfma_f32_16x16x32_bf16(   \
          aR[ii][kc], bR[(jB) + jj][kc], acc[(iB) + ii][(jB) + jj], 0, 0, 0); }
#define MID_BAR do { __builtin_amdgcn_s_barrier();                           \
    asm volatile("s_waitcnt lgkmcnt(0)" ::: "memory");                       \
    __builtin_amdgcn_sched_barrier(0);                                       \
    __builtin_amdgcn_s_setprio(1); } while (0)
#define END_BAR do { __builtin_amdgcn_s_setprio(0);                          \
    __builtin_amdgcn_sched_barrier(0);                                       \
    __builtin_amdgcn_s_barrier(); } while (0)

template <bool F32OUT>
__global__ __launch_bounds__(512, 2)
void gemm_bt_256(const u16* __restrict__ A, const u16* __restrict__ W,
                 void* __restrict__ Cv, int K, int lda, int ldc)
{
  extern __shared__ __align__(16) u16 smem[];   // 65536 u16 = 128 KB
  u16* lA = smem;
  u16* lB = smem + 32768;

  const int tid  = threadIdx.x;
  const int wid  = tid >> 6, ln = tid & 63;
  const int quad = ln >> 4,  l15 = ln & 15;
  const int wr = wid >> 2, wc = wid & 3;        // wave grid 2(M) x 4(N)
  const int m0 = blockIdx.y * 256, n0 = blockIdx.x * 256;

  const floatx4 vzero = {0.f, 0.f, 0.f, 0.f};
  floatx4 acc[8][4];
#pragma unroll
  for (int i = 0; i < 8; ++i)
#pragma unroll
    for (int j = 0; j < 4; ++j) acc[i][j] = vzero;

  bf16x8 aR[4][2], bR[4][2];

  const int NT = K >> 6;    // K/64, even
  const int NI = NT >> 1;

  // ---- prologue: A(0), B(0), B(1); certify tile 0, keep B(1) in flight ----
  STG_A(0, 0); STG_A(0, 1); STG_B(0, 0); STG_B(0, 1); STG_B(1, 0); STG_B(1, 1);
  asm volatile("s_waitcnt vmcnt(4)" ::: "memory");
  __builtin_amdgcn_s_barrier();

#pragma unroll 1
  for (int i = 0; i < NI; ++i) {
    const int t = 2 * i;
    const bool more = (i + 1 < NI);

    // phase 0: tile t (buf0), quadrant m0-3 x n0-1
    RDS_A03(0); RDS_B01(0);
    STG_A(t + 1, 0);
    MID_BAR; MFMAQ(0, 0); END_BAR;

    // phase 1: m0-3 x n2-3
    RDS_B23(0);
    STG_A(t + 1, 1);
    MID_BAR; MFMAQ(0, 2); END_BAR;

    // phase 2: m4-7 x n0-1
    RDS_A47(0);
    if (more) STG_B(t + 2, 0);
    MID_BAR; MFMAQ(4, 0); END_BAR;

    // phase 3: m4-7 x n2-3; certify A(t+1)+B(t+1) (oldest 8 of 12)
    if (more) {
      STG_B(t + 2, 1);
      asm volatile("s_waitcnt vmcnt(4)" ::: "memory");
    } else {
      asm volatile("s_waitcnt vmcnt(0)" ::: "memory");
    }
    MID_BAR; MFMAQ(4, 2); END_BAR;

    // phase 4: tile t+1 (buf1), m0-3 x n0-1
    RDS_A03(1); RDS_B01(1);
    if (more) STG_A(t + 2, 0);
    MID_BAR; MFMAQ(0, 0); END_BAR;

    // phase 5: m0-3 x n2-3
    RDS_B23(1);
    if (more) STG_A(t + 2, 1);
    MID_BAR; MFMAQ(0, 2); END_BAR;

    // phase 6: m4-7 x n0-1
    RDS_A47(1);
    if (more) STG_B(t + 3, 0);
    MID_BAR; MFMAQ(4, 0); END_BAR;

    // phase 7: m4-7 x n2-3; certify A(t+2)+B(t+2)
    if (more) {
      STG_B(t + 3, 1);
      asm volatile("s_waitcnt vmcnt(4)" ::: "memory");
    } else {
      asm volatile("s_waitcnt vmcnt(0)" ::: "memory");
    }
    MID_BAR; MFMAQ(4, 2); END_BAR;
  }

  // epilogue: C/D layout row = quad*4 + reg, col = lane&15 (m89-verified)
#pragma unroll
  for (int i = 0; i < 8; ++i)
#pragma unroll
    for (int r = 0; r < 4; ++r) {
      const int row = m0 + wr * 128 + i * 16 + quad * 4 + r;
      if (F32OUT) {
        float* cp = (float*)Cv + (size_t)row * ldc + n0 + wc * 64 + l15;
#pragma unroll
        for (int j = 0; j < 4; ++j) cp[j * 16] = acc[i][j][r];
      } else {
        u16* cp = (u16*)Cv + (size_t)row * ldc + n0 + wc * 64 + l15;
#pragma unroll
        for (int j = 0; j < 4; ++j) cp[j * 16] = f2bf(acc[i][j][r]);
      }
    }
}

// ---------------------------------------------------------------------------
// RoPE in place on q,k slices of qkv (bf16).
// ---------------------------------------------------------------------------
__global__ __launch_bounds__(256)
void rope_inplace(u16* __restrict__ qkv)
{
  const int s = blockIdx.x, b = blockIdx.y;
  const int tid = threadIdx.x;
  __shared__ float cs[64], sn[64];
  if (tid < 64) {
    const float inv = powf(10000.0f, -((float)tid) / 64.0f);
    float s_, c_;
    sincosf((float)s * inv, &s_, &c_);
    cs[tid] = c_; sn[tid] = s_;
  }
  __syncthreads();
  u16* base = qkv + ((size_t)b * S_ + s) * QKVN_;
  for (int p = tid; p < NH_ * 64; p += 256) {          // q: 16 heads x 64 pairs
    const int h = p >> 6, i = p & 63;
    u16* hp = base + h * 128;
    const float x1 = bf2f(hp[i]);
    const float x2 = bf2f(hp[64 + i]);
    hp[i]      = f2bf(x1 * cs[i] - x2 * sn[i]);
    hp[64 + i] = f2bf(x2 * cs[i] + x1 * sn[i]);
  }
  for (int p = tid; p < NKV_ * 64; p += 256) {         // k: 4 heads x 64 pairs
    const int h = p >> 6, i = p & 63;
    u16* hp = base + NH_ * HD_ + h * 128;
    const float x1 = bf2f(hp[i]);
    const float x2 = bf2f(hp[64 + i]);
    hp[i]      = f2bf(x1 * cs[i] - x2 * sn[i]);
    hp[64 + i] = f2bf(x2 * cs[i] + x1 * sn[i]);
  }
}

// ---------------------------------------------------------------------------
// V (B,S,NKV,HD inside qkv) -> V^T (B,NKV,HD,S), coalesced both sides via an
// LDS transpose tile. 64 s-rows x 128 d per block. Stride 73 (odd) banks.
// ---------------------------------------------------------------------------
__global__ __launch_bounds__(256)
void v_transpose(const u16* __restrict__ qkv, u16* __restrict__ vt)
{
  const int s0  = blockIdx.x * 64;
  const int kvh = blockIdx.y;
  const int b   = blockIdx.z;
  const int tid = threadIdx.x;
  __shared__ u16 lT[128 * 73];   // [d][s], odd stride

  const u16* vsrc = qkv + ((size_t)b * S_ + s0) * QKVN_
                    + NH_ * HD_ + NKV_ * HD_ + kvh * HD_;
#pragma unroll
  for (int p = 0; p < 4; ++p) {
    const int idx = p * 256 + tid;       // 1024 chunks: 64 s-rows x 16 slots
    const int r = idx >> 4, c = idx & 15;
    union { uint4 v; u16 h[8]; } u;
    u.v = *(const uint4*)(vsrc + (size_t)r * QKVN_ + c * 8);
#pragma unroll
    for (int j = 0; j < 8; ++j)
      lT[(c * 8 + j) * 73 + r] = u.h[j];
  }
  __syncthreads();
  u16* vdst = vt + ((size_t)(b * NKV_ + kvh) * HD_) * S_ + s0;
#pragma unroll
  for (int p = 0; p < 4; ++p) {
    const int idx = p * 256 + tid;       // 1024 chunks: 128 d-rows x 8 chunks
    const int d = idx >> 3, rc = idx & 7;
    union { uint4 v; u16 h[8]; } o;
#pragma unroll
    for (int j = 0; j < 8; ++j)
      o.h[j] = lT[d * 73 + rc * 8 + j];
    *(uint4*)(vdst + (size_t)d * S_ + rc * 8) = o.v;
  }
}

// ---------------------------------------------------------------------------
// Flash attention, causal, GQA. Paired q-tiles {31-pi, pi} (uniform 33 key-
// tile iterations per block), flattened into one loop; K/V double-buffered
// LDS + global_load_lds DMA + counted vmcnt(8) + raw barriers.
// ---------------------------------------------------------------------------
#define LPP 68   // lP row pad: 64 + 4 (quad bank stride 8, ~2-way on writes)
#define KSLOT(key, s) ((key) * 128 + (((s) ^ ((key) & 7)) * 8))
#define VSLOT(d, s)   ((d) * 64  + (((s) ^ ((d) & 7)) * 8))

__global__ __launch_bounds__(256, 2)
void flash_attn(u16* __restrict__ qkv, const u16* __restrict__ vt_ws)
{
  const int pi = blockIdx.x;             // 0..15
  const int h  = blockIdx.y;
  const int b  = blockIdx.z;
  const int tid  = threadIdx.x;
  const int w    = tid >> 6, ln = tid & 63;
  const int quad = ln >> 4,  l15 = ln & 15;
  const int kvh  = h >> 2;

  const int qtA = 31 - pi, qtB = pi;     // heavy half first
  const int itA = qtA + 1;
  const int nIt = itA + qtB + 1;         // 33, uniform across blocks

  __shared__ __align__(16) u16 lK[2][64 * 128];    // 2 x 16 KB
  __shared__ __align__(16) u16 lVt[2][128 * 64];   // 2 x 16 KB
  __shared__ __align__(16) u16 lP[4][16 * LPP];    // 8.7 KB, per-wave

  const float scale = 0.08838834764831845f;  // 1/sqrt(128)
  const u16* kbase = qkv + (size_t)b * S_ * QKVN_ + NH_ * HD_ + kvh * HD_;
  const u16* vbase = vt_ws + (size_t)(b * NKV_ + kvh) * HD_ * S_;
  const floatx4 vzero = {0.f, 0.f, 0.f, 0.f};

  // Q fragments for BOTH halves up front. A[m=lane&15][k=quad*8+j], 4 chunks.
  bf16x8 qFA[4], qFB[4];
  {
    const u16* qpA = qkv + ((size_t)(b * S_) + qtA * 64 + w * 16 + l15) * QKVN_ + h * HD_;
    const u16* qpB = qkv + ((size_t)(b * S_) + qtB * 64 + w * 16 + l15) * QKVN_ + h * HD_;
#pragma unroll
    for (int c = 0; c < 4; ++c) {
      qFA[c] = *(const bf16x8*)(qpA + c * 32 + quad * 8);
      qFB[c] = *(const bf16x8*)(qpB + c * 32 + quad * 8);
    }
  }

  float m_i[4], l_i[4];
  floatx4 Oacc[8];
#pragma unroll
  for (int r = 0; r < 4; ++r) { m_i[r] = -1e30f; l_i[r] = 0.f; }
#pragma unroll
  for (int t = 0; t < 8; ++t) Oacc[t] = vzero;

  bf16x8 qF[4];
#pragma unroll
  for (int c = 0; c < 4; ++c) qF[c] = qFA[c];
  int qtC = qtA;
  int qrow0 = qtA * 64 + w * 16;

  // ---- prologue: stage tile (A, kt=0) into buffer 0 (8 gloads/wave) ----
#pragma unroll
  for (int p = 0; p < 4; ++p) {
    const int idx = (w * 4 + p) * 64 + ln;         // 0..1023 16B-chunks
    const int key = idx >> 4, ks = idx & 15;
    GLOAD_LDS16(kbase + (size_t)key * QKVN_ + ((ks ^ (key & 7)) * 8),
                lK[0] + (w * 4 + p) * 512);
    const int d = idx >> 3, vs = idx & 7;
    GLOAD_LDS16(vbase + (size_t)d * S_ + ((vs ^ (d & 7)) * 8),
                lVt[0] + (w * 4 + p) * 512);
  }

#pragma unroll 1
  for (int it = 0; it < nIt; ++it) {
    const int ktC = (it < itA) ? it : (it - itA);
    const u16* lKc = lK[it & 1];
    const u16* lVc = lVt[it & 1];
    const bool pf = (it + 1 < nIt);
    if (pf) {
      // issue next tile's 8 DMA loads; they stay in flight across the barrier
      const int ktN = (it + 1 < itA) ? (it + 1) : (it + 1 - itA);
      u16* lKn = lK[(it + 1) & 1];
      u16* lVn = lVt[(it + 1) & 1];
#pragma unroll
      for (int p = 0; p < 4; ++p) {
        const int idx = (w * 4 + p) * 64 + ln;
        const int key = idx >> 4, ks = idx & 15;
        GLOAD_LDS16(kbase + (size_t)(ktN * 64 + key) * QKVN_ + ((ks ^ (key & 7)) * 8),
                    lKn + (w * 4 + p) * 512);
        const int d = idx >> 3, vs = idx & 7;
        GLOAD_LDS16(vbase + (size_t)d * S_ + ktN * 64 + ((vs ^ (d & 7)) * 8),
                    lVn + (w * 4 + p) * 512);
      }
      asm volatile("s_waitcnt vmcnt(8)" ::: "memory");   // this tile done; next in flight
    } else {
      asm volatile("s_waitcnt vmcnt(0)" ::: "memory");
    }
    __builtin_amdgcn_s_barrier();                  // raw: no vmcnt(0) drain
    __builtin_amdgcn_sched_barrier(0);

    // S = Q K^T : four 16-key column tiles
    floatx4 sc[4];
    __builtin_amdgcn_s_setprio(1);
#pragma unroll
    for (int nt = 0; nt < 4; ++nt) {
      floatx4 a = vzero;
      const int keyloc = nt * 16 + l15;
#pragma unroll
      for (int c = 0; c < 4; ++c) {
        const bf16x8 kF = *(const bf16x8*)(lKc + KSLOT(keyloc, c * 4 + quad));
        a = __builtin_amdgcn_mfma_f32_16x16x32_bf16(qF[c], kF, a, 0, 0, 0);
      }
      sc[nt] = a;
    }
    __builtin_amdgcn_s_setprio(0);

    // online softmax (q row = quad*4+r; 16 lanes hold 4x16 keys)
    float pr[4][4];
#pragma unroll
    for (int r = 0; r < 4; ++r) {
      const int qrow = qrow0 + quad * 4 + r;
      float s[4];
#pragma unroll
      for (int nt = 0; nt < 4; ++nt) {
        const int key0 = ktC * 64 + nt * 16 + l15;
        s[nt] = sc[nt][r] * scale + ((key0 <= qrow) ? 0.f : -1e9f);
      }
      float mx = fmaxf(fmaxf(s[0], s[1]), fmaxf(s[2], s[3]));
#pragma unroll
      for (int off = 1; off < 16; off <<= 1) mx = fmaxf(mx, __shfl_xor(mx, off, 64));
      const float mn = fmaxf(m_i[r], mx);
      const float alpha = __expf(m_i[r] - mn);
      float sm = 0.f;
#pragma unroll
      for (int nt = 0; nt < 4; ++nt) {
        const float p = __expf(s[nt] - mn);
        pr[nt][r] = p;
        sm += p;
      }
#pragma unroll
      for (int off = 1; off < 16; off <<= 1) sm += __shfl_xor(sm, off, 64);
      l_i[r] = l_i[r] * alpha + sm;
      m_i[r] = mn;
#pragma unroll
      for (int t = 0; t < 8; ++t) Oacc[t][r] *= alpha;
    }

    // P (16x64) -> per-wave LDS staging (A-operand layout, padded rows).
    // Wave-local region: same-wave ds_write -> ds_read ordered via lgkmcnt.
#pragma unroll
    for (int nt = 0; nt < 4; ++nt)
#pragma unroll
      for (int r = 0; r < 4; ++r)
        lP[w][(quad * 4 + r) * LPP + nt * 16 + l15] = f2bf(pr[nt][r]);

    // O += P V : A = P[m=qrow][k=key], B = V^T[n=d][k=key]; 2 k-chunks of 32
    {
      const bf16x8 pF0 = *(const bf16x8*)(&lP[w][l15 * LPP + quad * 8]);
      const bf16x8 pF1 = *(const bf16x8*)(&lP[w][l15 * LPP + 32 + quad * 8]);
      __builtin_amdgcn_s_setprio(1);
#pragma unroll
      for (int t = 0; t < 8; ++t) {
        const int d = t * 16 + l15;
        const bf16x8 vF0 = *(const bf16x8*)(lVc + VSLOT(d, quad));
        const bf16x8 vF1 = *(const bf16x8*)(lVc + VSLOT(d, 4 + quad));
        Oacc[t] = __builtin_amdgcn_mfma_f32_16x16x32_bf16(pF0, vF0, Oacc[t], 0, 0, 0);
        Oacc[t] = __builtin_amdgcn_mfma_f32_16x16x32_bf16(pF1, vF1, Oacc[t], 0, 0, 0);
      }
      __builtin_amdgcn_s_setprio(0);
    }

    // half boundary: store this half's output, reset state for next half.
    if (ktC == qtC) {
      float linv[4];
#pragma unroll
      for (int r = 0; r < 4; ++r) linv[r] = 1.0f / l_i[r];
#pragma unroll
      for (int t = 0; t < 8; ++t) {
        const int d = t * 16 + l15;
#pragma unroll
        for (int r = 0; r < 4; ++r) {
          const int qrow = qrow0 + quad * 4 + r;
          qkv[((size_t)(b * S_ + qrow)) * QKVN_ + h * HD_ + d] =
              f2bf(Oacc[t][r] * linv[r]);
        }
      }
      if (pf) {   // switch to half B
        qtC = qtB;
        qrow0 = qtB * 64 + w * 16;
#pragma unroll
        for (int c = 0; c < 4; ++c) qF[c] = qFB[c];
#pragma unroll
        for (int r = 0; r < 4; ++r) { m_i[r] = -1e30f; l_i[r] = 0.f; }
#pragma unroll
        for (int t = 0; t < 8; ++t) Oacc[t] = vzero;
      }
    }

    __builtin_amdgcn_s_barrier();   // all waves done reading lK/lVt[cur]
  }
}

// ---------------------------------------------------------------------------
// d_out is FLOAT32 (reference output dtype). Its first 16.8 MB serve as bf16
// scratch (xb, then vt); gemm2 overwrites all of d_out last.
// ws: [qkv 12.58M u16][slotW 6.29M u16] = 37.75 MB.
// ---------------------------------------------------------------------------
extern "C" void kernel_launch(void* const* d_in, const int* in_sizes, int n_in,
                              void* d_out, int out_size, void* d_ws, size_t ws_size,
                              hipStream_t stream)
{
  (void)in_sizes; (void)n_in; (void)out_size; (void)ws_size;
  const float* x     = (const float*)d_in[0];   // f32 per reference dtypes
  // d_in[1] = position_ids (arange) — analytic; d_in[2] = causal mask — analytic
  const float* w_qkv = (const float*)d_in[3];
  const float* w_o   = (const float*)d_in[4];
  float* out = (float*)d_out;                   // f32 output

  const int nX  = B_ * S_ * HID_;               // 8.39M
  const int nWq = QKVN_ * HID_;                 // 6.29M
  const int nWo = HID_ * HID_;                  // 4.19M

  u16* ws    = (u16*)d_ws;
  u16* qkv   = ws;                              // 12.58M u16
  u16* slotW = qkv + (size_t)(B_ * S_) * QKVN_; // 6.29M u16
  u16* xb    = (u16*)d_out;                     // bf16 scratch inside f32 d_out
  u16* vt_ws = (u16*)d_out;                     // reused after gemm1 (2.10M u16)

  const dim3 blk(256);
  // 0) casts (f32 -> bf16): x -> d_out scratch, w_qkv -> slotW
  cast_f32_bf16<<<nX  / 2048, blk, 0, stream>>>(x,     xb,    nX);
  cast_f32_bf16<<<nWq / 2048, blk, 0, stream>>>(w_qkv, slotW, nWq);
  // 1) qkv = x @ w_qkv^T   (M=4096, N=3072, K=2048), bf16 out; 8-phase 256^2
  gemm_bt_256<false><<<dim3(QKVN_ / 256, (B_ * S_) / 256), dim3(512), 131072, stream>>>(
      xb, slotW, qkv, HID_, HID_, QKVN_);
  // 2) RoPE in place on q,k (xb dead after gemm1)
  rope_inplace<<<dim3(S_, B_), blk, 0, stream>>>(qkv);
  // 2a) V -> V^T into d_out scratch (coalesced transpose)
  v_transpose<<<dim3(S_ / 64, NKV_, B_), blk, 0, stream>>>(qkv, vt_ws);
  // 2b) cast w_o into slotW (wqb dead after gemm1)
  cast_f32_bf16<<<nWo / 2048, blk, 0, stream>>>(w_o, slotW, nWo);
  // 3) causal GQA flash attention (paired tiles + dbuf counted-vmcnt + T5)
  flash_attn<<<dim3(16, NH_, B_), blk, 0, stream>>>(qkv, vt_ws);
  // 4) out = attn @ w_o^T  (M=4096, N=2048, K=2048), f32 out, attn lda=3072;
  //    8-phase 256^2 (128 blocks = half grid, still ~781 TF effective > 128^2's ~480)
  gemm_bt_256<true><<<dim3(HID_ / 256, (B_ * S_) / 256), dim3(512), 131072, stream>>>(
      qkv, slotW, out, HID_, QKVN_, HID_);
}

// Round 7
// 336.718 us; speedup vs baseline: 1.0206x; 1.0206x over previous
//
#include <hip/hip_runtime.h>
#include <hip/hip_bf16.h>
#include <cstdint>
#include <cstddef>

typedef unsigned short u16;
typedef __attribute__((ext_vector_type(8))) __bf16 bf16x8;
typedef __attribute__((ext_vector_type(4))) float floatx4;

#define B_    2
#define S_    2048
#define HID_  2048
#define NH_   16
#define NKV_  4
#define HD_   128
#define QKVN_ 3072   // NH*HD + 2*NKV*HD

__device__ __forceinline__ float bf2f(u16 u) {
  union { unsigned int i; float f; } v; v.i = ((unsigned int)u) << 16; return v.f;
}
__device__ __forceinline__ u16 f2bf(float f) {
  union { float f; unsigned int i; } v; v.f = f;
  unsigned int u = v.i;
  return (u16)((u + 0x7fffu + ((u >> 16) & 1u)) >> 16);  // RNE
}

// async global->LDS, 16B per lane; lane i lands at (wave-uniform base) + i*16.
#define GLOAD_LDS16(gp, lp)                                                  \
  __builtin_amdgcn_global_load_lds(                                          \
      (__attribute__((address_space(1))) void*)(gp),                         \
      (__attribute__((address_space(3))) void*)(lp), 16, 0, 0)

// ---------------------------------------------------------------------------
// f32 -> bf16 (RNE), 8 elements/thread, 16B stores. n % 2048 == 0.
// ---------------------------------------------------------------------------
__global__ __launch_bounds__(256)
void cast_f32_bf16(const float* __restrict__ in, u16* __restrict__ out, int n)
{
  const int i = (blockIdx.x * 256 + threadIdx.x) * 8;
  if (i >= n) return;
  const float4 a = *(const float4*)(in + i);
  const float4 b = *(const float4*)(in + i + 4);
  union { u16 h[8]; uint4 v; } o;
  o.h[0] = f2bf(a.x); o.h[1] = f2bf(a.y); o.h[2] = f2bf(a.z); o.h[3] = f2bf(a.w);
  o.h[4] = f2bf(b.x); o.h[5] = f2bf(b.y); o.h[6] = f2bf(b.z); o.h[7] = f2bf(b.w);
  *(uint4*)(out + i) = o.v;
}

// ---------------------------------------------------------------------------
// 128x128 GEMM with the flash-verified DMA pipeline: C = A @ W^T, bf16 in,
// fp32 accum. 4 waves, 64x64 out/wave, BK=64. Double-buffered 64 KB LDS
// (-> 2 blocks/CU, restoring inter-block latency overlap), staged via
// global_load_lds; next tile's 8 DMAs issued before compute + counted
// s_waitcnt vmcnt(8) + raw barriers (2/iter). Both-sides XOR chunk swizzle
// (source chunk c^(row&7); ds_read same XOR — involution, rule #21).
// ---------------------------------------------------------------------------
template <bool F32OUT>
__global__ __launch_bounds__(256, 2)
void gemm_bt_128(const u16* __restrict__ A, const u16* __restrict__ W,
                 void* __restrict__ Cv, int N, int K, int lda, int ldc)
{
  __shared__ __align__(16) u16 lA[2][128 * 64];   // 2 x 16 KB
  __shared__ __align__(16) u16 lB[2][128 * 64];   // 2 x 16 KB
  const int tid  = threadIdx.x;
  const int w    = tid >> 6, ln = tid & 63;
  const int quad = ln >> 4,  l15 = ln & 15;
  const int m0 = blockIdx.y * 128, n0 = blockIdx.x * 128;
  const int waveM = (w >> 1) * 64, waveN = (w & 1) * 64;

  const floatx4 vzero = {0.f, 0.f, 0.f, 0.f};
  floatx4 acc[4][4];
#pragma unroll
  for (int i = 0; i < 4; ++i)
#pragma unroll
    for (int j = 0; j < 4; ++j) acc[i][j] = vzero;

  const int NT = K >> 6;

  // stage K-tile kt into buffer buf: 1024 chunks/matrix, 8 DMA instr/thread.
#define STAGE128(kt, buf)                                                     \
  { _Pragma("unroll")                                                         \
    for (int p = 0; p < 4; ++p) {                                             \
      const int L = (p * 4 + w) * 64 + ln;                                    \
      const int row = L >> 3, c = L & 7;                                      \
      const int cs = (c ^ (row & 7)) * 8;                                     \
      GLOAD_LDS16(A + (size_t)(m0 + row) * lda + (kt) * 64 + cs,              \
                  lA[buf] + L * 8);                                           \
      GLOAD_LDS16(W + (size_t)(n0 + row) * K + (kt) * 64 + cs,                \
                  lB[buf] + L * 8);                                           \
    } }

  STAGE128(0, 0);

#pragma unroll 1
  for (int t = 0; t < NT; ++t) {
    if (t + 1 < NT) {
      STAGE128(t + 1, (t + 1) & 1);   // 8 DMAs stay in flight across barrier
      asm volatile("s_waitcnt vmcnt(8)" ::: "memory");   // tile t certified
    } else {
      asm volatile("s_waitcnt vmcnt(0)" ::: "memory");
    }
    __builtin_amdgcn_s_barrier();
    __builtin_amdgcn_sched_barrier(0);

    const u16* a = lA[t & 1];
    const u16* b = lB[t & 1];
#pragma unroll
    for (int kk = 0; kk < 64; kk += 32) {
      bf16x8 aF[4], bF[4];
      const int cbase = (kk >> 3) + quad;       // chunk holding k = kk+quad*8
#pragma unroll
      for (int tt = 0; tt < 4; ++tt) {
        const int rowA = waveM + tt * 16 + l15;
        aF[tt] = *(const bf16x8*)(a + rowA * 64 + (cbase ^ (l15 & 7)) * 8);
        const int rowB = waveN + tt * 16 + l15;
        bF[tt] = *(const bf16x8*)(b + rowB * 64 + (cbase ^ (l15 & 7)) * 8);
      }
      __builtin_amdgcn_s_setprio(1);
#pragma unroll
      for (int i = 0; i < 4; ++i)
#pragma unroll
        for (int j = 0; j < 4; ++j)
          acc[i][j] = __builtin_amdgcn_mfma_f32_16x16x32_bf16(aF[i], bF[j], acc[i][j], 0, 0, 0);
      __builtin_amdgcn_s_setprio(0);
    }

    __builtin_amdgcn_s_barrier();   // readers done; buf[(t+1)&1] safe next iter
  }
#undef STAGE128

  // epilogue: C/D layout row = quad*4+reg, col = lane&15 (m89-verified)
#pragma unroll
  for (int i = 0; i < 4; ++i)
#pragma unroll
    for (int r = 0; r < 4; ++r) {
      const int row = m0 + waveM + i * 16 + quad * 4 + r;
      if (F32OUT) {
        float* cp = (float*)Cv + (size_t)row * ldc + n0 + waveN + l15;
#pragma unroll
        for (int j = 0; j < 4; ++j) cp[j * 16] = acc[i][j][r];
      } else {
        u16* cp = (u16*)Cv + (size_t)row * ldc + n0 + waveN + l15;
#pragma unroll
        for (int j = 0; j < 4; ++j) cp[j * 16] = f2bf(acc[i][j][r]);
      }
    }
}

// ---------------------------------------------------------------------------
// RoPE in place on q,k slices of qkv (bf16).
// ---------------------------------------------------------------------------
__global__ __launch_bounds__(256)
void rope_inplace(u16* __restrict__ qkv)
{
  const int s = blockIdx.x, b = blockIdx.y;
  const int tid = threadIdx.x;
  __shared__ float cs[64], sn[64];
  if (tid < 64) {
    const float inv = powf(10000.0f, -((float)tid) / 64.0f);
    float s_, c_;
    sincosf((float)s * inv, &s_, &c_);
    cs[tid] = c_; sn[tid] = s_;
  }
  __syncthreads();
  u16* base = qkv + ((size_t)b * S_ + s) * QKVN_;
  for (int p = tid; p < NH_ * 64; p += 256) {          // q: 16 heads x 64 pairs
    const int h = p >> 6, i = p & 63;
    u16* hp = base + h * 128;
    const float x1 = bf2f(hp[i]);
    const float x2 = bf2f(hp[64 + i]);
    hp[i]      = f2bf(x1 * cs[i] - x2 * sn[i]);
    hp[64 + i] = f2bf(x2 * cs[i] + x1 * sn[i]);
  }
  for (int p = tid; p < NKV_ * 64; p += 256) {         // k: 4 heads x 64 pairs
    const int h = p >> 6, i = p & 63;
    u16* hp = base + NH_ * HD_ + h * 128;
    const float x1 = bf2f(hp[i]);
    const float x2 = bf2f(hp[64 + i]);
    hp[i]      = f2bf(x1 * cs[i] - x2 * sn[i]);
    hp[64 + i] = f2bf(x2 * cs[i] + x1 * sn[i]);
  }
}

// ---------------------------------------------------------------------------
// V (B,S,NKV,HD inside qkv) -> V^T (B,NKV,HD,S), coalesced both sides via an
// LDS transpose tile. 64 s-rows x 128 d per block. Stride 73 (odd) banks.
// ---------------------------------------------------------------------------
__global__ __launch_bounds__(256)
void v_transpose(const u16* __restrict__ qkv, u16* __restrict__ vt)
{
  const int s0  = blockIdx.x * 64;
  const int kvh = blockIdx.y;
  const int b   = blockIdx.z;
  const int tid = threadIdx.x;
  __shared__ u16 lT[128 * 73];   // [d][s], odd stride

  const u16* vsrc = qkv + ((size_t)b * S_ + s0) * QKVN_
                    + NH_ * HD_ + NKV_ * HD_ + kvh * HD_;
#pragma unroll
  for (int p = 0; p < 4; ++p) {
    const int idx = p * 256 + tid;       // 1024 chunks: 64 s-rows x 16 slots
    const int r = idx >> 4, c = idx & 15;
    union { uint4 v; u16 h[8]; } u;
    u.v = *(const uint4*)(vsrc + (size_t)r * QKVN_ + c * 8);
#pragma unroll
    for (int j = 0; j < 8; ++j)
      lT[(c * 8 + j) * 73 + r] = u.h[j];
  }
  __syncthreads();
  u16* vdst = vt + ((size_t)(b * NKV_ + kvh) * HD_) * S_ + s0;
#pragma unroll
  for (int p = 0; p < 4; ++p) {
    const int idx = p * 256 + tid;       // 1024 chunks: 128 d-rows x 8 chunks
    const int d = idx >> 3, rc = idx & 7;
    union { uint4 v; u16 h[8]; } o;
#pragma unroll
    for (int j = 0; j < 8; ++j)
      o.h[j] = lT[d * 73 + rc * 8 + j];
    *(uint4*)(vdst + (size_t)d * S_ + rc * 8) = o.v;
  }
}

// ---------------------------------------------------------------------------
// Flash attention, causal, GQA. Paired q-tiles {31-pi, pi} (uniform 33 key-
// tile iterations per block), flattened into one loop; K/V double-buffered
// LDS + global_load_lds DMA + counted vmcnt(8) + raw barriers.
// ---------------------------------------------------------------------------
#define LPP 68   // lP row pad: 64 + 4 (quad bank stride 8, ~2-way on writes)
#define KSLOT(key, s) ((key) * 128 + (((s) ^ ((key) & 7)) * 8))
#define VSLOT(d, s)   ((d) * 64  + (((s) ^ ((d) & 7)) * 8))

__global__ __launch_bounds__(256, 2)
void flash_attn(u16* __restrict__ qkv, const u16* __restrict__ vt_ws)
{
  const int pi = blockIdx.x;             // 0..15
  const int h  = blockIdx.y;
  const int b  = blockIdx.z;
  const int tid  = threadIdx.x;
  const int w    = tid >> 6, ln = tid & 63;
  const int quad = ln >> 4,  l15 = ln & 15;
  const int kvh  = h >> 2;

  const int qtA = 31 - pi, qtB = pi;     // heavy half first
  const int itA = qtA + 1;
  const int nIt = itA + qtB + 1;         // 33, uniform across blocks

  __shared__ __align__(16) u16 lK[2][64 * 128];    // 2 x 16 KB
  __shared__ __align__(16) u16 lVt[2][128 * 64];   // 2 x 16 KB
  __shared__ __align__(16) u16 lP[4][16 * LPP];    // 8.7 KB, per-wave

  const float scale = 0.08838834764831845f;  // 1/sqrt(128)
  const u16* kbase = qkv + (size_t)b * S_ * QKVN_ + NH_ * HD_ + kvh * HD_;
  const u16* vbase = vt_ws + (size_t)(b * NKV_ + kvh) * HD_ * S_;
  const floatx4 vzero = {0.f, 0.f, 0.f, 0.f};

  // Q fragments for BOTH halves up front. A[m=lane&15][k=quad*8+j], 4 chunks.
  bf16x8 qFA[4], qFB[4];
  {
    const u16* qpA = qkv + ((size_t)(b * S_) + qtA * 64 + w * 16 + l15) * QKVN_ + h * HD_;
    const u16* qpB = qkv + ((size_t)(b * S_) + qtB * 64 + w * 16 + l15) * QKVN_ + h * HD_;
#pragma unroll
    for (int c = 0; c < 4; ++c) {
      qFA[c] = *(const bf16x8*)(qpA + c * 32 + quad * 8);
      qFB[c] = *(const bf16x8*)(qpB + c * 32 + quad * 8);
    }
  }

  float m_i[4], l_i[4];
  floatx4 Oacc[8];
#pragma unroll
  for (int r = 0; r < 4; ++r) { m_i[r] = -1e30f; l_i[r] = 0.f; }
#pragma unroll
  for (int t = 0; t < 8; ++t) Oacc[t] = vzero;

  bf16x8 qF[4];
#pragma unroll
  for (int c = 0; c < 4; ++c) qF[c] = qFA[c];
  int qtC = qtA;
  int qrow0 = qtA * 64 + w * 16;

  // ---- prologue: stage tile (A, kt=0) into buffer 0 (8 gloads/wave) ----
#pragma unroll
  for (int p = 0; p < 4; ++p) {
    const int idx = (w * 4 + p) * 64 + ln;         // 0..1023 16B-chunks
    const int key = idx >> 4, ks = idx & 15;
    GLOAD_LDS16(kbase + (size_t)key * QKVN_ + ((ks ^ (key & 7)) * 8),
                lK[0] + (w * 4 + p) * 512);
    const int d = idx >> 3, vs = idx & 7;
    GLOAD_LDS16(vbase + (size_t)d * S_ + ((vs ^ (d & 7)) * 8),
                lVt[0] + (w * 4 + p) * 512);
  }

#pragma unroll 1
  for (int it = 0; it < nIt; ++it) {
    const int ktC = (it < itA) ? it : (it - itA);
    const u16* lKc = lK[it & 1];
    const u16* lVc = lVt[it & 1];
    const bool pf = (it + 1 < nIt);
    if (pf) {
      // issue next tile's 8 DMA loads; they stay in flight across the barrier
      const int ktN = (it + 1 < itA) ? (it + 1) : (it + 1 - itA);
      u16* lKn = lK[(it + 1) & 1];
      u16* lVn = lVt[(it + 1) & 1];
#pragma unroll
      for (int p = 0; p < 4; ++p) {
        const int idx = (w * 4 + p) * 64 + ln;
        const int key = idx >> 4, ks = idx & 15;
        GLOAD_LDS16(kbase + (size_t)(ktN * 64 + key) * QKVN_ + ((ks ^ (key & 7)) * 8),
                    lKn + (w * 4 + p) * 512);
        const int d = idx >> 3, vs = idx & 7;
        GLOAD_LDS16(vbase + (size_t)d * S_ + ktN * 64 + ((vs ^ (d & 7)) * 8),
                    lVn + (w * 4 + p) * 512);
      }
      asm volatile("s_waitcnt vmcnt(8)" ::: "memory");   // this tile done; next in flight
    } else {
      asm volatile("s_waitcnt vmcnt(0)" ::: "memory");
    }
    __builtin_amdgcn_s_barrier();                  // raw: no vmcnt(0) drain
    __builtin_amdgcn_sched_barrier(0);

    // S = Q K^T : four 16-key column tiles
    floatx4 sc[4];
    __builtin_amdgcn_s_setprio(1);
#pragma unroll
    for (int nt = 0; nt < 4; ++nt) {
      floatx4 a = vzero;
      const int keyloc = nt * 16 + l15;
#pragma unroll
      for (int c = 0; c < 4; ++c) {
        const bf16x8 kF = *(const bf16x8*)(lKc + KSLOT(keyloc, c * 4 + quad));
        a = __builtin_amdgcn_mfma_f32_16x16x32_bf16(qF[c], kF, a, 0, 0, 0);
      }
      sc[nt] = a;
    }
    __builtin_amdgcn_s_setprio(0);

    // online softmax (q row = quad*4+r; 16 lanes hold 4x16 keys)
    float pr[4][4];
#pragma unroll
    for (int r = 0; r < 4; ++r) {
      const int qrow = qrow0 + quad * 4 + r;
      float s[4];
#pragma unroll
      for (int nt = 0; nt < 4; ++nt) {
        const int key0 = ktC * 64 + nt * 16 + l15;
        s[nt] = sc[nt][r] * scale + ((key0 <= qrow) ? 0.f : -1e9f);
      }
      float mx = fmaxf(fmaxf(s[0], s[1]), fmaxf(s[2], s[3]));
#pragma unroll
      for (int off = 1; off < 16; off <<= 1) mx = fmaxf(mx, __shfl_xor(mx, off, 64));
      const float mn = fmaxf(m_i[r], mx);
      const float alpha = __expf(m_i[r] - mn);
      float sm = 0.f;
#pragma unroll
      for (int nt = 0; nt < 4; ++nt) {
        const float p = __expf(s[nt] - mn);
        pr[nt][r] = p;
        sm += p;
      }
#pragma unroll
      for (int off = 1; off < 16; off <<= 1) sm += __shfl_xor(sm, off, 64);
      l_i[r] = l_i[r] * alpha + sm;
      m_i[r] = mn;
#pragma unroll
      for (int t = 0; t < 8; ++t) Oacc[t][r] *= alpha;
    }

    // P (16x64) -> per-wave LDS staging (A-operand layout, padded rows).
    // Wave-local region: same-wave ds_write -> ds_read ordered via lgkmcnt.
#pragma unroll
    for (int nt = 0; nt < 4; ++nt)
#pragma unroll
      for (int r = 0; r < 4; ++r)
        lP[w][(quad * 4 + r) * LPP + nt * 16 + l15] = f2bf(pr[nt][r]);

    // O += P V : A = P[m=qrow][k=key], B = V^T[n=d][k=key]; 2 k-chunks of 32
    {
      const bf16x8 pF0 = *(const bf16x8*)(&lP[w][l15 * LPP + quad * 8]);
      const bf16x8 pF1 = *(const bf16x8*)(&lP[w][l15 * LPP + 32 + quad * 8]);
      __builtin_amdgcn_s_setprio(1);
#pragma unroll
      for (int t = 0; t < 8; ++t) {
        const int d = t * 16 + l15;
        const bf16x8 vF0 = *(const bf16x8*)(lVc + VSLOT(d, quad));
        const bf16x8 vF1 = *(const bf16x8*)(lVc + VSLOT(d, 4 + quad));
        Oacc[t] = __builtin_amdgcn_mfma_f32_16x16x32_bf16(pF0, vF0, Oacc[t], 0, 0, 0);
        Oacc[t] = __builtin_amdgcn_mfma_f32_16x16x32_bf16(pF1, vF1, Oacc[t], 0, 0, 0);
      }
      __builtin_amdgcn_s_setprio(0);
    }

    // half boundary: store this half's output, reset state for next half.
    if (ktC == qtC) {
      float linv[4];
#pragma unroll
      for (int r = 0; r < 4; ++r) linv[r] = 1.0f / l_i[r];
#pragma unroll
      for (int t = 0; t < 8; ++t) {
        const int d = t * 16 + l15;
#pragma unroll
        for (int r = 0; r < 4; ++r) {
          const int qrow = qrow0 + quad * 4 + r;
          qkv[((size_t)(b * S_ + qrow)) * QKVN_ + h * HD_ + d] =
              f2bf(Oacc[t][r] * linv[r]);
        }
      }
      if (pf) {   // switch to half B
        qtC = qtB;
        qrow0 = qtB * 64 + w * 16;
#pragma unroll
        for (int c = 0; c < 4; ++c) qF[c] = qFB[c];
#pragma unroll
        for (int r = 0; r < 4; ++r) { m_i[r] = -1e30f; l_i[r] = 0.f; }
#pragma unroll
        for (int t = 0; t < 8; ++t) Oacc[t] = vzero;
      }
    }

    __builtin_amdgcn_s_barrier();   // all waves done reading lK/lVt[cur]
  }
}

// ---------------------------------------------------------------------------
// d_out is FLOAT32 (reference output dtype). Its first 16.8 MB serve as bf16
// scratch (xb, then vt); gemm2 overwrites all of d_out last.
// ws: [qkv 12.58M u16][slotW 6.29M u16] = 37.75 MB.
// ---------------------------------------------------------------------------
extern "C" void kernel_launch(void* const* d_in, const int* in_sizes, int n_in,
                              void* d_out, int out_size, void* d_ws, size_t ws_size,
                              hipStream_t stream)
{
  (void)in_sizes; (void)n_in; (void)out_size; (void)ws_size;
  const float* x     = (const float*)d_in[0];   // f32 per reference dtypes
  // d_in[1] = position_ids (arange) — analytic; d_in[2] = causal mask — analytic
  const float* w_qkv = (const float*)d_in[3];
  const float* w_o   = (const float*)d_in[4];
  float* out = (float*)d_out;                   // f32 output

  const int nX  = B_ * S_ * HID_;               // 8.39M
  const int nWq = QKVN_ * HID_;                 // 6.29M
  const int nWo = HID_ * HID_;                  // 4.19M

  u16* ws    = (u16*)d_ws;
  u16* qkv   = ws;                              // 12.58M u16
  u16* slotW = qkv + (size_t)(B_ * S_) * QKVN_; // 6.29M u16
  u16* xb    = (u16*)d_out;                     // bf16 scratch inside f32 d_out
  u16* vt_ws = (u16*)d_out;                     // reused after gemm1 (2.10M u16)

  const dim3 blk(256);
  // 0) casts (f32 -> bf16): x -> d_out scratch, w_qkv -> slotW
  cast_f32_bf16<<<nX  / 2048, blk, 0, stream>>>(x,     xb,    nX);
  cast_f32_bf16<<<nWq / 2048, blk, 0, stream>>>(w_qkv, slotW, nWq);
  // 1) qkv = x @ w_qkv^T   (M=4096, N=3072, K=2048), bf16 out; DMA-dbuf 128^2
  gemm_bt_128<false><<<dim3(QKVN_ / 128, (B_ * S_) / 128), blk, 0, stream>>>(
      xb, slotW, qkv, QKVN_, HID_, HID_, QKVN_);
  // 2) RoPE in place on q,k (xb dead after gemm1)
  rope_inplace<<<dim3(S_, B_), blk, 0, stream>>>(qkv);
  // 2a) V -> V^T into d_out scratch (coalesced transpose)
  v_transpose<<<dim3(S_ / 64, NKV_, B_), blk, 0, stream>>>(qkv, vt_ws);
  // 2b) cast w_o into slotW (wqb dead after gemm1)
  cast_f32_bf16<<<nWo / 2048, blk, 0, stream>>>(w_o, slotW, nWo);
  // 3) causal GQA flash attention (paired tiles + dbuf counted-vmcnt + T5)
  flash_attn<<<dim3(16, NH_, B_), blk, 0, stream>>>(qkv, vt_ws);
  // 4) out = attn @ w_o^T  (M=4096, N=2048, K=2048), f32 out, attn lda=3072;
  //    full 512-block grid (2 blocks/CU)
  gemm_bt_128<true><<<dim3(HID_ / 128, (B_ * S_) / 128), blk, 0, stream>>>(
      qkv, slotW, out, HID_, HID_, QKVN_, HID_);
}